// Round 5
// baseline (268.505 us; speedup 1.0000x reference)
//
#include <hip/hip_runtime.h>
#include <string.h>

#define NN 30000
#define NE 480000
#define CAP 96
#define SCALE 0.0625f

typedef __attribute__((ext_vector_type(8))) _Float16 f16x8;
typedef __attribute__((ext_vector_type(4))) float f32x4;
typedef __attribute__((ext_vector_type(4))) int i32x4;

__device__ __forceinline__ unsigned short f2h(float f) {
    _Float16 h = (_Float16)f;
    unsigned short u;
    memcpy(&u, &h, 2);
    return u;
}

__device__ __forceinline__ void gload16(const void* g, void* l) {
    __builtin_amdgcn_global_load_lds(
        (const __attribute__((address_space(1))) unsigned int*)g,
        (__attribute__((address_space(3))) unsigned int*)l, 16, 0, 0);
}

// ---------------- LayerNorm -> fp16 x ----------------
__global__ __launch_bounds__(256) void ln_kernel(const float* __restrict__ s,
                                                 const float* __restrict__ gamma,
                                                 const float* __restrict__ beta,
                                                 unsigned short* __restrict__ xh) {
    const int n = blockIdx.x;
    const int c = threadIdx.x;
    float v = s[n * 256 + c];
    float sum = v, sq = v * v;
    for (int o = 32; o; o >>= 1) {
        sum += __shfl_down(sum, o, 64);
        sq  += __shfl_down(sq,  o, 64);
    }
    __shared__ float ssum[4], ssq[4];
    const int wave = c >> 6, lane = c & 63;
    if (lane == 0) { ssum[wave] = sum; ssq[wave] = sq; }
    __syncthreads();
    float ts = ssum[0] + ssum[1] + ssum[2] + ssum[3];
    float tq = ssq[0]  + ssq[1]  + ssq[2]  + ssq[3];
    float mu  = ts * (1.0f / 256.0f);
    float var = tq * (1.0f / 256.0f) - mu * mu;
    float x = (v - mu) * rsqrtf(var + 1e-5f) * gamma[c] + beta[c];
    xh[n * 256 + c] = f2h(x);
}

// ---------------- Wqkv [256,768] f32 -> WT [768,256] fp16 ----------------
__global__ __launch_bounds__(256) void wt_kernel(const float* __restrict__ W,
                                                 unsigned short* __restrict__ WT) {
    const int idx = blockIdx.x * 256 + threadIdx.x;
    if (idx < 768 * 256) {
        const int n = idx >> 8;
        const int k = idx & 255;
        WT[idx] = f2h(W[k * 768 + n]);
    }
}

__global__ __launch_bounds__(256) void zero_kernel(int* __restrict__ p, int n) {
    const int i = blockIdx.x * 256 + threadIdx.x;
    if (i < n) p[i] = 0;
}

__global__ __launch_bounds__(256) void scatter_kernel(const int* __restrict__ src,
                                                      const int* __restrict__ dst,
                                                      int* __restrict__ cursor,
                                                      unsigned short* __restrict__ col) {
    const int e = blockIdx.x * 256 + threadIdx.x;
    if (e < NE) {
        const int d = dst[e];
        const int slot = atomicAdd(&cursor[d], 1);
        if (slot < CAP) col[d * CAP + slot] = (unsigned short)src[e];
    }
}

// ---------------- GEMM: m97-style, XCD-banded bm, sliced epilogue ----------------
#define BM 128
#define BN 128
#define BK 32
#define CSTRIDE 136
#define MTILES 235   // ceil(30000/128)

__global__ __launch_bounds__(256) void gemm_kernel(const unsigned short* __restrict__ A,
                                                   const unsigned short* __restrict__ B,
                                                   unsigned short* __restrict__ qb,
                                                   unsigned short* __restrict__ kb,
                                                   unsigned short* __restrict__ vb) {
    // XCD-banded swizzle: flat id f -> xcd = f%8 (matches round-robin block->XCD),
    // each XCD owns a contiguous band of 30 bm-tiles (A band = 1.97 MB, L2-resident)
    const int f   = blockIdx.x;          // 0..1439
    const int xcd = f & 7;
    const int i   = f >> 3;              // 0..179
    const int bmi = xcd * 30 + i / 6;
    if (bmi >= MTILES) return;
    const int bm = bmi * BM;
    const int by = i % 6;
    const int bn = by * BN;

    __shared__ unsigned short smem[BM * CSTRIDE];
    unsigned short* As = smem;
    unsigned short* Bs = smem + 4096;

    const int tid  = threadIdx.x;
    const int lane = tid & 63;
    const int wave = tid >> 6;
    const int wm = (wave & 1) * 64;
    const int wn = (wave >> 1) * 64;
    const int l16  = lane & 15;
    const int quad = lane >> 4;

    const int srow = wave * 16 + (lane >> 2);
    const int ko   = (lane & 3) * 8;

    int gmA0 = bm + srow;       if (gmA0 >= NN) gmA0 = NN - 1;
    int gmA1 = bm + srow + 64;  if (gmA1 >= NN) gmA1 = NN - 1;
    const int gnB0 = bn + srow;
    const int gnB1 = bn + srow + 64;

    f32x4 acc[4][4] = {};

    for (int kt = 0; kt < 256; kt += BK) {
        gload16(A + (size_t)gmA0 * 256 + kt + ko, &As[(wave * 16) * 32]);
        gload16(A + (size_t)gmA1 * 256 + kt + ko, &As[(64 + wave * 16) * 32]);
        gload16(B + (size_t)gnB0 * 256 + kt + ko, &Bs[(wave * 16) * 32]);
        gload16(B + (size_t)gnB1 * 256 + kt + ko, &Bs[(64 + wave * 16) * 32]);
        __syncthreads();

        f16x8 af[4], bfr[4];
        #pragma unroll
        for (int ii = 0; ii < 4; ii++)
            af[ii]  = *(const f16x8*)(&As[(wm + ii * 16 + l16) * 32 + quad * 8]);
        #pragma unroll
        for (int j = 0; j < 4; j++)
            bfr[j] = *(const f16x8*)(&Bs[(wn + j * 16 + l16) * 32 + quad * 8]);
        #pragma unroll
        for (int ii = 0; ii < 4; ii++)
            #pragma unroll
            for (int j = 0; j < 4; j++)
                acc[ii][j] = __builtin_amdgcn_mfma_f32_16x16x32_f16(af[ii], bfr[j], acc[ii][j], 0, 0, 0);
        __syncthreads();
    }

    #pragma unroll
    for (int ii = 0; ii < 4; ii++)
        #pragma unroll
        for (int j = 0; j < 4; j++)
            #pragma unroll
            for (int r = 0; r < 4; r++)
                smem[(wm + ii * 16 + quad * 4 + r) * CSTRIDE + wn + j * 16 + l16] =
                    f2h(acc[ii][j][r]);
    __syncthreads();

    const int sector  = by >> 1;                 // 0=q,1=k,2=v
    const int colhalf = (by & 1) * 128;
    unsigned short* dbuf = (sector == 0) ? qb : ((sector == 1) ? kb : vb);
    const int row  = tid >> 1;
    const int cseg = (tid & 1) * 64;
    const int grow = bm + row;
    if (grow < NN) {
        #pragma unroll
        for (int k = 0; k < 8; k++) {
            i32x4 val = *(const i32x4*)(&smem[row * CSTRIDE + cseg + k * 8]);
            const int c = colhalf + cseg + k * 8;        // 0..255, 8-aligned
            // sliced layout: buf[slice][node][32]
            *(i32x4*)(dbuf + ((size_t)(c >> 5) * NN + grow) * 32 + (c & 31)) = val;
        }
    }
}

// ---------------- edge: slice-per-XCD, wave-per-node, 4 edges/iter ----------------
__global__ __launch_bounds__(256) void edge_kernel(const unsigned short* __restrict__ qs,  // [8][NN][32]
                                                   const unsigned short* __restrict__ vs,  // [8][NN][32]
                                                   const unsigned short* __restrict__ ks,  // [8][NN][32]
                                                   const int* __restrict__ cursor,
                                                   const unsigned short* __restrict__ col, // [NN][CAP]
                                                   float* __restrict__ out) {
    const int x    = blockIdx.x;            // slice 0..7 -> XCD x (heuristic)
    const int wave = threadIdx.x >> 6;
    const int lane = threadIdx.x & 63;
    const int n    = blockIdx.y * 4 + wave; // NN % 4 == 0

    int deg = cursor[n];
    if (deg > CAP) deg = CAP;

    __shared__ unsigned short sidx[4][CAP];
    if (lane < CAP / 2)
        ((unsigned int*)&sidx[wave][0])[lane] = ((const unsigned int*)(col + n * CAP))[lane];
    // wave-coherent LDS write->read

    const int cpair = lane & 15;            // channel pair 2*cpair, 2*cpair+1
    const int eg    = lane >> 4;            // edge group 0..3

    union H2 { unsigned int u; _Float16 h[2]; };
    const size_t sbase = (size_t)x * NN * 32;
    H2 kw;
    kw.u = *(const unsigned int*)(ks + sbase + (size_t)n * 32 + 2 * cpair);
    const float kk0 = (float)kw.h[0] * SCALE;
    const float kk1 = (float)kw.h[1] * SCALE;

    const unsigned short* qsl = qs + sbase + 2 * cpair;
    const unsigned short* vsl = vs + sbase + 2 * cpair;

    float z0 = 0.f, z1 = 0.f, a0 = 0.f, a1 = 0.f;

    for (int i = 0; i < deg; i += 4) {
        const int e  = i + eg;
        const int ok = (e < deg);
        const int s  = sidx[wave][ok ? e : 0];
        H2 qd, vd;
        qd.u = *(const unsigned int*)(qsl + (size_t)s * 32);
        vd.u = *(const unsigned int*)(vsl + (size_t)s * 32);
        const float fmask = ok ? 1.0f : 0.0f;
        const float w0 = __expf((float)qd.h[0] * kk0) * fmask;
        const float w1 = __expf((float)qd.h[1] * kk1) * fmask;
        z0 += w0; z1 += w1;
        a0 += w0 * (float)vd.h[0];
        a1 += w1 * (float)vd.h[1];
    }

    // combine the 4 edge-groups (lanes with same cpair are 16 apart)
    z0 += __shfl_xor(z0, 16, 64);  z0 += __shfl_xor(z0, 32, 64);
    z1 += __shfl_xor(z1, 16, 64);  z1 += __shfl_xor(z1, 32, 64);
    a0 += __shfl_xor(a0, 16, 64);  a0 += __shfl_xor(a0, 32, 64);
    a1 += __shfl_xor(a1, 16, 64);  a1 += __shfl_xor(a1, 32, 64);

    if (lane < 16) {
        float2 o;
        o.x = (deg > 0) ? a0 / z0 : 0.0f;
        o.y = (deg > 0) ? a1 / z1 : 0.0f;
        *(float2*)(out + (size_t)n * 256 + x * 32 + 2 * cpair) = o;
    }
}

extern "C" void kernel_launch(void* const* d_in, const int* in_sizes, int n_in,
                              void* d_out, int out_size, void* d_ws, size_t ws_size,
                              hipStream_t stream) {
    const float* s     = (const float*)d_in[0];
    const float* Wqkv  = (const float*)d_in[1];
    const float* gamma = (const float*)d_in[2];
    const float* beta  = (const float*)d_in[3];
    const int*   src   = (const int*)d_in[4];
    const int*   dst   = (const int*)d_in[5];
    float* out = (float*)d_out;

    char* ws = (char*)d_ws;
    unsigned short* xh  = (unsigned short*)(ws);                    // 15,360,000 B
    unsigned short* WT  = (unsigned short*)(ws + 15360000);         //    393,216 B
    unsigned short* qs  = (unsigned short*)(ws + 15753216);         // 15,360,000 B [8][NN][32]
    unsigned short* ks  = (unsigned short*)(ws + 31113216);         // 15,360,000 B
    unsigned short* vs  = (unsigned short*)(ws + 46473216);         // 15,360,000 B
    int*            cur = (int*)(ws + 61833216);                    //    120,000 B
    unsigned short* col = (unsigned short*)(ws + 61953216);         //  5,760,000 B (~67.7 MB)

    ln_kernel<<<NN, 256, 0, stream>>>(s, gamma, beta, xh);
    wt_kernel<<<(768 * 256 + 255) / 256, 256, 0, stream>>>(Wqkv, WT);
    zero_kernel<<<(NN + 255) / 256, 256, 0, stream>>>(cur, NN);
    scatter_kernel<<<(NE + 255) / 256, 256, 0, stream>>>(src, dst, cur, col);
    gemm_kernel<<<1440, 256, 0, stream>>>(xh, WT, qs, ks, vs);
    edge_kernel<<<dim3(8, NN / 4), 256, 0, stream>>>(qs, vs, ks, cur, col, out);
}

// Round 6
// 236.549 us; speedup vs baseline: 1.1351x; 1.1351x over previous
//
#include <hip/hip_runtime.h>
#include <string.h>

#define NN 30000
#define NE 480000
#define CAP 96
#define SCALE 0.0625f
#define KSC (0.0625f * 1.44269504f)   // SCALE * log2(e), for exp2-based softmax

typedef __attribute__((ext_vector_type(8))) _Float16 f16x8;
typedef __attribute__((ext_vector_type(4))) float f32x4;
typedef __attribute__((ext_vector_type(4))) int i32x4;

__device__ __forceinline__ unsigned short f2h(float f) {
    _Float16 h = (_Float16)f;
    unsigned short u;
    memcpy(&u, &h, 2);
    return u;
}

__device__ __forceinline__ void gload16(const void* g, void* l) {
    __builtin_amdgcn_global_load_lds(
        (const __attribute__((address_space(1))) unsigned int*)g,
        (__attribute__((address_space(3))) unsigned int*)l, 16, 0, 0);
}

// ---------------- LayerNorm -> fp16 x ----------------
__global__ __launch_bounds__(256) void ln_kernel(const float* __restrict__ s,
                                                 const float* __restrict__ gamma,
                                                 const float* __restrict__ beta,
                                                 unsigned short* __restrict__ xh) {
    const int n = blockIdx.x;
    const int c = threadIdx.x;
    float v = s[n * 256 + c];
    float sum = v, sq = v * v;
    for (int o = 32; o; o >>= 1) {
        sum += __shfl_down(sum, o, 64);
        sq  += __shfl_down(sq,  o, 64);
    }
    __shared__ float ssum[4], ssq[4];
    const int wave = c >> 6, lane = c & 63;
    if (lane == 0) { ssum[wave] = sum; ssq[wave] = sq; }
    __syncthreads();
    float ts = ssum[0] + ssum[1] + ssum[2] + ssum[3];
    float tq = ssq[0]  + ssq[1]  + ssq[2]  + ssq[3];
    float mu  = ts * (1.0f / 256.0f);
    float var = tq * (1.0f / 256.0f) - mu * mu;
    float x = (v - mu) * rsqrtf(var + 1e-5f) * gamma[c] + beta[c];
    xh[n * 256 + c] = f2h(x);
}

// ---------------- Wqkv [256,768] f32 -> WT [768,256] fp16 ----------------
__global__ __launch_bounds__(256) void wt_kernel(const float* __restrict__ W,
                                                 unsigned short* __restrict__ WT) {
    const int idx = blockIdx.x * 256 + threadIdx.x;
    if (idx < 768 * 256) {
        const int n = idx >> 8;
        const int k = idx & 255;
        WT[idx] = f2h(W[k * 768 + n]);
    }
}

__global__ __launch_bounds__(256) void zero_kernel(int* __restrict__ p, int n) {
    const int i = blockIdx.x * 256 + threadIdx.x;
    if (i < n) p[i] = 0;
}

__global__ __launch_bounds__(256) void scatter_kernel(const int* __restrict__ src,
                                                      const int* __restrict__ dst,
                                                      int* __restrict__ cursor,
                                                      unsigned short* __restrict__ col) {
    const int e = blockIdx.x * 256 + threadIdx.x;
    if (e < NE) {
        const int d = dst[e];
        const int slot = atomicAdd(&cursor[d], 1);
        if (slot < CAP) col[d * CAP + slot] = (unsigned short)src[e];
    }
}

// ---------------- GEMM: m97-style, XCD-banded bm, sliced epilogue ----------------
#define BM 128
#define BN 128
#define BK 32
#define CSTRIDE 136
#define MTILES 235   // ceil(30000/128)

__global__ __launch_bounds__(256) void gemm_kernel(const unsigned short* __restrict__ A,
                                                   const unsigned short* __restrict__ B,
                                                   unsigned short* __restrict__ qb,
                                                   unsigned short* __restrict__ kb,
                                                   unsigned short* __restrict__ vb) {
    const int f   = blockIdx.x;          // 0..1439
    const int xcd = f & 7;
    const int i   = f >> 3;              // 0..179
    const int bmi = xcd * 30 + i / 6;
    if (bmi >= MTILES) return;
    const int bm = bmi * BM;
    const int by = i % 6;
    const int bn = by * BN;

    __shared__ unsigned short smem[BM * CSTRIDE];
    unsigned short* As = smem;
    unsigned short* Bs = smem + 4096;

    const int tid  = threadIdx.x;
    const int lane = tid & 63;
    const int wave = tid >> 6;
    const int wm = (wave & 1) * 64;
    const int wn = (wave >> 1) * 64;
    const int l16  = lane & 15;
    const int quad = lane >> 4;

    const int srow = wave * 16 + (lane >> 2);
    const int ko   = (lane & 3) * 8;

    int gmA0 = bm + srow;       if (gmA0 >= NN) gmA0 = NN - 1;
    int gmA1 = bm + srow + 64;  if (gmA1 >= NN) gmA1 = NN - 1;
    const int gnB0 = bn + srow;
    const int gnB1 = bn + srow + 64;

    f32x4 acc[4][4] = {};

    for (int kt = 0; kt < 256; kt += BK) {
        gload16(A + (size_t)gmA0 * 256 + kt + ko, &As[(wave * 16) * 32]);
        gload16(A + (size_t)gmA1 * 256 + kt + ko, &As[(64 + wave * 16) * 32]);
        gload16(B + (size_t)gnB0 * 256 + kt + ko, &Bs[(wave * 16) * 32]);
        gload16(B + (size_t)gnB1 * 256 + kt + ko, &Bs[(64 + wave * 16) * 32]);
        __syncthreads();

        f16x8 af[4], bfr[4];
        #pragma unroll
        for (int ii = 0; ii < 4; ii++)
            af[ii]  = *(const f16x8*)(&As[(wm + ii * 16 + l16) * 32 + quad * 8]);
        #pragma unroll
        for (int j = 0; j < 4; j++)
            bfr[j] = *(const f16x8*)(&Bs[(wn + j * 16 + l16) * 32 + quad * 8]);
        #pragma unroll
        for (int ii = 0; ii < 4; ii++)
            #pragma unroll
            for (int j = 0; j < 4; j++)
                acc[ii][j] = __builtin_amdgcn_mfma_f32_16x16x32_f16(af[ii], bfr[j], acc[ii][j], 0, 0, 0);
        __syncthreads();
    }

    #pragma unroll
    for (int ii = 0; ii < 4; ii++)
        #pragma unroll
        for (int j = 0; j < 4; j++)
            #pragma unroll
            for (int r = 0; r < 4; r++)
                smem[(wm + ii * 16 + quad * 4 + r) * CSTRIDE + wn + j * 16 + l16] =
                    f2h(acc[ii][j][r]);
    __syncthreads();

    const int sector  = by >> 1;                 // 0=q,1=k,2=v
    const int colhalf = (by & 1) * 128;
    unsigned short* dbuf = (sector == 0) ? qb : ((sector == 1) ? kb : vb);
    const int row  = tid >> 1;
    const int cseg = (tid & 1) * 64;
    const int grow = bm + row;
    if (grow < NN) {
        #pragma unroll
        for (int k = 0; k < 8; k++) {
            i32x4 val = *(const i32x4*)(&smem[row * CSTRIDE + cseg + k * 8]);
            const int c = colhalf + cseg + k * 8;
            *(i32x4*)(dbuf + ((size_t)(c >> 5) * NN + grow) * 32 + (c & 31)) = val;
        }
    }
}

// ---------------- edge: slice-per-XCD, 16 nodes/block, 4 nodes/wave ----------------
__global__ __launch_bounds__(256) void edge_kernel(const unsigned short* __restrict__ qs,  // [8][NN][32]
                                                   const unsigned short* __restrict__ vs,  // [8][NN][32]
                                                   const unsigned short* __restrict__ ks,  // [8][NN][32]
                                                   const int* __restrict__ cursor,
                                                   const unsigned short* __restrict__ col, // [NN][CAP]
                                                   float* __restrict__ out) {
    const int x    = blockIdx.x;            // slice 0..7 -> XCD x (round-robin)
    const int nb   = blockIdx.y * 16;       // block's 16 nodes
    const int tid  = threadIdx.x;
    const int wave = tid >> 6;
    const int lane = tid & 63;

    __shared__ unsigned short scol[16][CAP];   // 3072 B
    __shared__ int sdeg[16];

    // stage degs + cols for 16 nodes
    if (tid < 16) {
        int d = cursor[nb + tid];
        sdeg[tid] = (d > CAP) ? CAP : d;
    }
    {
        const unsigned int* colu = (const unsigned int*)(col + (size_t)nb * CAP);
        unsigned int* scolu = (unsigned int*)&scol[0][0];
        #pragma unroll
        for (int j = 0; j < 3; j++) scolu[tid + j * 256] = colu[tid + j * 256];
    }
    __syncthreads();

    const int g     = lane >> 4;            // node-in-wave 0..3
    const int cpair = lane & 15;            // channel pair (2 ch)
    const int li    = wave * 4 + g;         // local node 0..15
    const int n     = nb + li;

    const int mydeg = sdeg[li];
    int dmax = sdeg[wave * 4];
    dmax = max(dmax, sdeg[wave * 4 + 1]);
    dmax = max(dmax, sdeg[wave * 4 + 2]);
    dmax = max(dmax, sdeg[wave * 4 + 3]);

    union H2 { unsigned int u; _Float16 h[2]; };
    const size_t sbase = (size_t)x * NN * 32;
    H2 kw;
    kw.u = *(const unsigned int*)(ks + sbase + (size_t)n * 32 + 2 * cpair);
    const float kk0 = (float)kw.h[0] * KSC;   // log2e folded: exp(q*k*SCALE) = exp2(q*kk)
    const float kk1 = (float)kw.h[1] * KSC;

    const unsigned short* qp = qs + sbase + 2 * cpair;
    const unsigned short* vp = vs + sbase + 2 * cpair;

    float z0 = 0.f, z1 = 0.f, a0 = 0.f, a1 = 0.f;

    for (int i = 0; i < dmax; ++i) {
        const bool ok = (i < mydeg);
        const int  s  = scol[li][ok ? i : 0];
        H2 qd, vd;
        qd.u = *(const unsigned int*)(qp + (size_t)s * 32);
        vd.u = *(const unsigned int*)(vp + (size_t)s * 32);
        float w0 = __builtin_exp2f((float)qd.h[0] * kk0);
        float w1 = __builtin_exp2f((float)qd.h[1] * kk1);
        w0 = ok ? w0 : 0.0f;
        w1 = ok ? w1 : 0.0f;
        z0 += w0; z1 += w1;
        a0 += w0 * (float)vd.h[0];
        a1 += w1 * (float)vd.h[1];
    }

    float2 o;
    o.x = (mydeg > 0) ? a0 / z0 : 0.0f;
    o.y = (mydeg > 0) ? a1 / z1 : 0.0f;
    *(float2*)(out + (size_t)n * 256 + x * 32 + 2 * cpair) = o;
}

extern "C" void kernel_launch(void* const* d_in, const int* in_sizes, int n_in,
                              void* d_out, int out_size, void* d_ws, size_t ws_size,
                              hipStream_t stream) {
    const float* s     = (const float*)d_in[0];
    const float* Wqkv  = (const float*)d_in[1];
    const float* gamma = (const float*)d_in[2];
    const float* beta  = (const float*)d_in[3];
    const int*   src   = (const int*)d_in[4];
    const int*   dst   = (const int*)d_in[5];
    float* out = (float*)d_out;

    char* ws = (char*)d_ws;
    unsigned short* xh  = (unsigned short*)(ws);                    // 15,360,000 B
    unsigned short* WT  = (unsigned short*)(ws + 15360000);         //    393,216 B
    unsigned short* qs  = (unsigned short*)(ws + 15753216);         // 15,360,000 B [8][NN][32]
    unsigned short* ks  = (unsigned short*)(ws + 31113216);         // 15,360,000 B
    unsigned short* vs  = (unsigned short*)(ws + 46473216);         // 15,360,000 B
    int*            cur = (int*)(ws + 61833216);                    //    120,000 B
    unsigned short* col = (unsigned short*)(ws + 61953216);         //  5,760,000 B (~67.7 MB)

    ln_kernel<<<NN, 256, 0, stream>>>(s, gamma, beta, xh);
    wt_kernel<<<(768 * 256 + 255) / 256, 256, 0, stream>>>(Wqkv, WT);
    zero_kernel<<<(NN + 255) / 256, 256, 0, stream>>>(cur, NN);
    scatter_kernel<<<(NE + 255) / 256, 256, 0, stream>>>(src, dst, cur, col);
    gemm_kernel<<<1440, 256, 0, stream>>>(xh, WT, qs, ks, vs);
    edge_kernel<<<dim3(8, NN / 16), 256, 0, stream>>>(qs, vs, ks, cur, col, out);
}